// Round 1
// baseline (1022.751 us; speedup 1.0000x reference)
//
#include <hip/hip_runtime.h>

// LightGCN propagation: 3x SpMM over fixed COO graph + batched dot epilogue.
// Strategy: build dst-CSR once per call (hist -> scan -> scatter), then each
// SpMM is a pure gather (1 wave per node, lane=dim, no float atomics).
// acc kept only for the 8192 gathered rows (users+items), not all 150K nodes.

#define N_USERS 50000
#define N_ITEMS 100000
#define N_NODES 150000
#define N_EDGES 2400000
#define DIM 64
#define BATCH 4096
#define NLAYERS 3

#define SCAN_CHUNK 1024
#define NB ((N_NODES + SCAN_CHUNK - 1) / SCAN_CHUNK)  // 147 blocks

__global__ void copy4_kernel(const float4* __restrict__ src, float4* __restrict__ dst, int n4) {
    int i = blockIdx.x * 256 + threadIdx.x;
    if (i < n4) dst[i] = src[i];
}

__global__ void hist_kernel(const int* __restrict__ dst, int* __restrict__ cnt) {
    int e = blockIdx.x * 256 + threadIdx.x;
    if (e < N_EDGES) atomicAdd(&cnt[dst[e]], 1);
}

// Pass 1: per-block (1024-elem chunk) sums of cnt
__global__ void scan1_kernel(const int* __restrict__ cnt, int* __restrict__ bsums) {
    int b = blockIdx.x, t = threadIdx.x;
    int base = b * SCAN_CHUNK + t * 4;
    int s = 0;
#pragma unroll
    for (int k = 0; k < 4; ++k) {
        int i = base + k;
        if (i < N_NODES) s += cnt[i];
    }
    __shared__ int sm[256];
    sm[t] = s;
    __syncthreads();
    for (int o = 128; o > 0; o >>= 1) {
        if (t < o) sm[t] += sm[t + o];
        __syncthreads();
    }
    if (t == 0) bsums[b] = sm[0];
}

// Pass 2: single-block exclusive scan of the NB (=147) block sums
__global__ void scan2_kernel(int* __restrict__ bsums) {
    int t = threadIdx.x;
    __shared__ int sm[256];
    int v = (t < NB) ? bsums[t] : 0;
    sm[t] = v;
    __syncthreads();
    for (int o = 1; o < 256; o <<= 1) {
        int add = (t >= o) ? sm[t - o] : 0;
        __syncthreads();
        sm[t] += add;
        __syncthreads();
    }
    if (t < NB) bsums[t] = sm[t] - v;  // exclusive prefix
}

// Pass 3: full exclusive scan -> row_start; cursor initialized to row_start
__global__ void scan3_kernel(const int* __restrict__ cnt, const int* __restrict__ bsums,
                             int* __restrict__ row_start, int* __restrict__ cursor) {
    int b = blockIdx.x, t = threadIdx.x;
    int base = b * SCAN_CHUNK + t * 4;
    int lp[4];
    int s = 0;
#pragma unroll
    for (int k = 0; k < 4; ++k) {
        int i = base + k;
        int v = (i < N_NODES) ? cnt[i] : 0;
        lp[k] = s;
        s += v;
    }
    __shared__ int sm[256];
    sm[t] = s;
    __syncthreads();
    for (int o = 1; o < 256; o <<= 1) {
        int add = (t >= o) ? sm[t - o] : 0;
        __syncthreads();
        sm[t] += add;
        __syncthreads();
    }
    int texcl = sm[t] - s;
    int o0 = bsums[b] + texcl;
#pragma unroll
    for (int k = 0; k < 4; ++k) {
        int i = base + k;
        if (i < N_NODES) {
            int rs = o0 + lp[k];
            row_start[i] = rs;
            cursor[i] = rs;
        }
    }
}

// Scatter edge payloads into CSR slots. After this, cursor[n] == row end.
__global__ void scatter_kernel(const int* __restrict__ src, const int* __restrict__ dst,
                               const float* __restrict__ vals, int* __restrict__ cursor,
                               int* __restrict__ ccol, float* __restrict__ cval) {
    int e = blockIdx.x * 256 + threadIdx.x;
    if (e < N_EDGES) {
        int d = dst[e];
        int p = atomicAdd(&cursor[d], 1);
        ccol[p] = src[e];
        cval[p] = vals[e];
    }
}

// One wave per node; lane = dim. row_end comes from post-scatter cursor.
__global__ __launch_bounds__(256) void spmm_kernel(
        const int* __restrict__ row_start, const int* __restrict__ row_end,
        const int* __restrict__ ccol, const float* __restrict__ cval,
        const float* __restrict__ xin, float* __restrict__ xout) {
    int n = (blockIdx.x * 256 + threadIdx.x) >> 6;
    int lane = threadIdx.x & 63;
    if (n >= N_NODES) return;
    int s = row_start[n];
    int e = row_end[n];
    float acc = 0.0f;
    for (int j = s; j < e; ++j) {
        int c = ccol[j];      // wave-uniform load (HW broadcast)
        float v = cval[j];
        acc += v * xin[c * DIM + lane];  // 256B coalesced gather per edge
    }
    xout[n * DIM + lane] = acc;
}

// acc over the 8192 gathered rows only. init=1: acc = x[node]; else acc += x[node].
__global__ void acc_kernel(const int* __restrict__ users, const int* __restrict__ items,
                           const float* __restrict__ x, float* __restrict__ acc, int init) {
    int idx = blockIdx.x * 256 + threadIdx.x;  // 2*BATCH*64 threads
    int r = idx >> 6;
    int lane = idx & 63;
    if (r >= 2 * BATCH) return;
    int node = (r < BATCH) ? users[r] : (N_USERS + items[r - BATCH]);
    float v = x[node * DIM + lane];
    if (init) acc[idx] = v;
    else acc[idx] += v;
}

// gamma[b] = dot(acc_u[b], acc_i[b]) / 16   (the /4 per side from mean-pool)
__global__ void dot_kernel(const float* __restrict__ acc, float* __restrict__ out) {
    int t = blockIdx.x * 256 + threadIdx.x;
    int b = t >> 6;
    int lane = t & 63;
    if (b >= BATCH) return;
    float p = acc[b * DIM + lane] * acc[(BATCH + b) * DIM + lane];
#pragma unroll
    for (int o = 32; o > 0; o >>= 1) p += __shfl_down(p, o, 64);
    if (lane == 0) out[b] = p * (1.0f / 16.0f);
}

extern "C" void kernel_launch(void* const* d_in, const int* in_sizes, int n_in,
                              void* d_out, int out_size, void* d_ws, size_t ws_size,
                              hipStream_t stream) {
    const float* emb_user = (const float*)d_in[0];
    const float* emb_item = (const float*)d_in[1];
    const float* vals     = (const float*)d_in[2];
    const int*   src      = (const int*)d_in[3];
    const int*   dst      = (const int*)d_in[4];
    const int*   users    = (const int*)d_in[5];
    const int*   items    = (const int*)d_in[6];
    float* out = (float*)d_out;

    char* ws = (char*)d_ws;
    size_t off = 0;
    auto walloc = [&](size_t bytes) -> void* {
        void* p = ws + off;
        off += (bytes + 255) & ~(size_t)255;
        return p;
    };
    float* bufA      = (float*)walloc((size_t)N_NODES * DIM * 4);   // 38.4 MB
    float* bufB      = (float*)walloc((size_t)N_NODES * DIM * 4);   // 38.4 MB
    int*   ccol      = (int*)  walloc((size_t)N_EDGES * 4);         // 9.6 MB
    float* cval      = (float*)walloc((size_t)N_EDGES * 4);         // 9.6 MB
    int*   cnt       = (int*)  walloc((size_t)N_NODES * 4);
    int*   row_start = (int*)  walloc((size_t)N_NODES * 4);
    int*   cursor    = (int*)  walloc((size_t)N_NODES * 4);
    int*   bsums     = (int*)  walloc((size_t)NB * 4);
    float* accs      = (float*)walloc((size_t)2 * BATCH * DIM * 4); // 2 MB

    // zero the histogram (ws is re-poisoned before every call)
    hipMemsetAsync(cnt, 0, (size_t)N_NODES * 4, stream);

    // x0 = concat(emb_user, emb_item)
    copy4_kernel<<<(N_USERS * DIM / 4 + 255) / 256, 256, 0, stream>>>(
        (const float4*)emb_user, (float4*)bufA, N_USERS * DIM / 4);
    copy4_kernel<<<(N_ITEMS * DIM / 4 + 255) / 256, 256, 0, stream>>>(
        (const float4*)emb_item, (float4*)(bufA + (size_t)N_USERS * DIM), N_ITEMS * DIM / 4);

    // Build CSR (dst-major)
    int eblocks = (N_EDGES + 255) / 256;
    hist_kernel<<<eblocks, 256, 0, stream>>>(dst, cnt);
    scan1_kernel<<<NB, 256, 0, stream>>>(cnt, bsums);
    scan2_kernel<<<1, 256, 0, stream>>>(bsums);
    scan3_kernel<<<NB, 256, 0, stream>>>(cnt, bsums, row_start, cursor);
    scatter_kernel<<<eblocks, 256, 0, stream>>>(src, dst, vals, cursor, ccol, cval);

    // acc init with layer-0 embeddings at gathered rows
    int ablocks = (2 * BATCH * DIM) / 256;  // 2048
    acc_kernel<<<ablocks, 256, 0, stream>>>(users, items, bufA, accs, 1);

    // 3 propagation layers
    int sblocks = (N_NODES + 3) / 4;  // 4 waves/block, 1 node/wave
    float* xin = bufA;
    float* xout = bufB;
    for (int l = 0; l < NLAYERS; ++l) {
        spmm_kernel<<<sblocks, 256, 0, stream>>>(row_start, cursor, ccol, cval, xin, xout);
        acc_kernel<<<ablocks, 256, 0, stream>>>(users, items, xout, accs, 0);
        float* t = xin; xin = xout; xout = t;
    }

    // gamma
    dot_kernel<<<(BATCH * DIM) / 256, 256, 0, stream>>>(accs, out);
}

// Round 2
// 623.110 us; speedup vs baseline: 1.6414x; 1.6414x over previous
//
#include <hip/hip_runtime.h>

// LightGCN propagation: 3x SpMM over fixed COO graph + batched dot epilogue.
// R2: SpMM restructured for memory-level parallelism — wave = 4 groups x 16
// lanes, each group gathers a different edge (float4/lane), 2x unrolled =
// 8 edges in flight per wave. Edge payload interleaved as int2{src,val}.
// Layer-0 reads emb tables directly (no concat copy).

#define N_USERS 50000
#define N_ITEMS 100000
#define N_NODES 150000
#define N_EDGES 2400000
#define DIM 64
#define BATCH 4096
#define NLAYERS 3

#define SCAN_CHUNK 1024
#define NB ((N_NODES + SCAN_CHUNK - 1) / SCAN_CHUNK)  // 147 blocks

__global__ void hist_kernel(const int* __restrict__ dst, int* __restrict__ cnt) {
    int e = blockIdx.x * 256 + threadIdx.x;
    if (e < N_EDGES) atomicAdd(&cnt[dst[e]], 1);
}

// Pass 1: per-block (1024-elem chunk) sums of cnt
__global__ void scan1_kernel(const int* __restrict__ cnt, int* __restrict__ bsums) {
    int b = blockIdx.x, t = threadIdx.x;
    int base = b * SCAN_CHUNK + t * 4;
    int s = 0;
#pragma unroll
    for (int k = 0; k < 4; ++k) {
        int i = base + k;
        if (i < N_NODES) s += cnt[i];
    }
    __shared__ int sm[256];
    sm[t] = s;
    __syncthreads();
    for (int o = 128; o > 0; o >>= 1) {
        if (t < o) sm[t] += sm[t + o];
        __syncthreads();
    }
    if (t == 0) bsums[b] = sm[0];
}

// Pass 2: single-block exclusive scan of the NB (=147) block sums
__global__ void scan2_kernel(int* __restrict__ bsums) {
    int t = threadIdx.x;
    __shared__ int sm[256];
    int v = (t < NB) ? bsums[t] : 0;
    sm[t] = v;
    __syncthreads();
    for (int o = 1; o < 256; o <<= 1) {
        int add = (t >= o) ? sm[t - o] : 0;
        __syncthreads();
        sm[t] += add;
        __syncthreads();
    }
    if (t < NB) bsums[t] = sm[t] - v;  // exclusive prefix
}

// Pass 3: full exclusive scan -> row_start; cursor initialized to row_start
__global__ void scan3_kernel(const int* __restrict__ cnt, const int* __restrict__ bsums,
                             int* __restrict__ row_start, int* __restrict__ cursor) {
    int b = blockIdx.x, t = threadIdx.x;
    int base = b * SCAN_CHUNK + t * 4;
    int lp[4];
    int s = 0;
#pragma unroll
    for (int k = 0; k < 4; ++k) {
        int i = base + k;
        int v = (i < N_NODES) ? cnt[i] : 0;
        lp[k] = s;
        s += v;
    }
    __shared__ int sm[256];
    sm[t] = s;
    __syncthreads();
    for (int o = 1; o < 256; o <<= 1) {
        int add = (t >= o) ? sm[t - o] : 0;
        __syncthreads();
        sm[t] += add;
        __syncthreads();
    }
    int texcl = sm[t] - s;
    int o0 = bsums[b] + texcl;
#pragma unroll
    for (int k = 0; k < 4; ++k) {
        int i = base + k;
        if (i < N_NODES) {
            int rs = o0 + lp[k];
            row_start[i] = rs;
            cursor[i] = rs;
        }
    }
}

// Scatter edge payloads (int2{src, val_bits}) into CSR slots.
__global__ void scatter_kernel(const int* __restrict__ src, const int* __restrict__ dst,
                               const float* __restrict__ vals, int* __restrict__ cursor,
                               int2* __restrict__ epair) {
    int e = blockIdx.x * 256 + threadIdx.x;
    if (e < N_EDGES) {
        int d = dst[e];
        int p = atomicAdd(&cursor[d], 1);
        int2 ev;
        ev.x = src[e];
        ev.y = __float_as_int(vals[e]);
        epair[p] = ev;
    }
}

// SpMM: one wave per node. Wave = 4 groups x 16 lanes; group g handles edges
// s+g, s+g+4, ... (2x unrolled -> 8 gathers in flight). Lane l of a group
// loads float4 l of the 64-float source row. Cross-group reduce via shfl_xor.
// Layer 0 gathers straight from the two embedding tables (split = N_USERS).
__global__ __launch_bounds__(256) void spmm_kernel(
        const int* __restrict__ row_start, const int* __restrict__ row_end,
        const int2* __restrict__ epair,
        const float* __restrict__ xu, const float* __restrict__ xi, int split,
        float* __restrict__ xout) {
    int n = (blockIdx.x * 256 + threadIdx.x) >> 6;   // 150000 = 4*37500 exact
    int lane = threadIdx.x & 63;
    int g = lane >> 4;        // edge group 0..3
    int l = lane & 15;        // float4 slot within row
    int s = row_start[n];
    int e = row_end[n];
    float4 acc = make_float4(0.f, 0.f, 0.f, 0.f);
    for (int j = s + g; j < e; j += 8) {
        int j2 = j + 4;
        bool p2 = j2 < e;
        int2 ev1 = epair[j];
        int2 ev2 = epair[p2 ? j2 : j];
        int c1 = ev1.x;
        int c2 = ev2.x;
        float v1 = __int_as_float(ev1.y);
        float v2 = p2 ? __int_as_float(ev2.y) : 0.f;
        const float4* b1 = (const float4*)((c1 < split) ? (xu + (size_t)c1 * DIM)
                                                        : (xi + (size_t)(c1 - split) * DIM));
        const float4* b2 = (const float4*)((c2 < split) ? (xu + (size_t)c2 * DIM)
                                                        : (xi + (size_t)(c2 - split) * DIM));
        float4 x1 = b1[l];
        float4 x2 = b2[l];
        acc.x += v1 * x1.x; acc.y += v1 * x1.y; acc.z += v1 * x1.z; acc.w += v1 * x1.w;
        acc.x += v2 * x2.x; acc.y += v2 * x2.y; acc.z += v2 * x2.z; acc.w += v2 * x2.w;
    }
    // sum the 4 groups' partials (lanes with equal l): xor-16 then xor-32
#pragma unroll
    for (int off = 16; off < 64; off <<= 1) {
        acc.x += __shfl_xor(acc.x, off, 64);
        acc.y += __shfl_xor(acc.y, off, 64);
        acc.z += __shfl_xor(acc.z, off, 64);
        acc.w += __shfl_xor(acc.w, off, 64);
    }
    if (g == 0) ((float4*)(xout + (size_t)n * DIM))[l] = acc;
}

// acc over the 8192 gathered rows only. init: acc = table row; else acc += x row.
__global__ void acc_init_kernel(const int* __restrict__ users, const int* __restrict__ items,
                                const float* __restrict__ emb_user, const float* __restrict__ emb_item,
                                float* __restrict__ acc) {
    int idx = blockIdx.x * 256 + threadIdx.x;  // 2*BATCH*64 threads
    int r = idx >> 6;
    int lane = idx & 63;
    const float* srcrow = (r < BATCH) ? (emb_user + (size_t)users[r] * DIM)
                                      : (emb_item + (size_t)items[r - BATCH] * DIM);
    acc[idx] = srcrow[lane];
}

__global__ void acc_add_kernel(const int* __restrict__ users, const int* __restrict__ items,
                               const float* __restrict__ x, float* __restrict__ acc) {
    int idx = blockIdx.x * 256 + threadIdx.x;
    int r = idx >> 6;
    int lane = idx & 63;
    int node = (r < BATCH) ? users[r] : (N_USERS + items[r - BATCH]);
    acc[idx] += x[(size_t)node * DIM + lane];
}

// gamma[b] = dot(acc_u[b], acc_i[b]) / 16
__global__ void dot_kernel(const float* __restrict__ acc, float* __restrict__ out) {
    int t = blockIdx.x * 256 + threadIdx.x;
    int b = t >> 6;
    int lane = t & 63;
    float p = acc[b * DIM + lane] * acc[(BATCH + b) * DIM + lane];
#pragma unroll
    for (int o = 32; o > 0; o >>= 1) p += __shfl_down(p, o, 64);
    if (lane == 0) out[b] = p * (1.0f / 16.0f);
}

extern "C" void kernel_launch(void* const* d_in, const int* in_sizes, int n_in,
                              void* d_out, int out_size, void* d_ws, size_t ws_size,
                              hipStream_t stream) {
    const float* emb_user = (const float*)d_in[0];
    const float* emb_item = (const float*)d_in[1];
    const float* vals     = (const float*)d_in[2];
    const int*   src      = (const int*)d_in[3];
    const int*   dst      = (const int*)d_in[4];
    const int*   users    = (const int*)d_in[5];
    const int*   items    = (const int*)d_in[6];
    float* out = (float*)d_out;

    char* ws = (char*)d_ws;
    size_t off = 0;
    auto walloc = [&](size_t bytes) -> void* {
        void* p = ws + off;
        off += (bytes + 255) & ~(size_t)255;
        return p;
    };
    float* bufA      = (float*)walloc((size_t)N_NODES * DIM * 4);   // 38.4 MB
    float* bufB      = (float*)walloc((size_t)N_NODES * DIM * 4);   // 38.4 MB
    int2*  epair     = (int2*) walloc((size_t)N_EDGES * 8);         // 19.2 MB
    int*   cnt       = (int*)  walloc((size_t)N_NODES * 4);
    int*   row_start = (int*)  walloc((size_t)N_NODES * 4);
    int*   cursor    = (int*)  walloc((size_t)N_NODES * 4);
    int*   bsums     = (int*)  walloc((size_t)NB * 4);
    float* accs      = (float*)walloc((size_t)2 * BATCH * DIM * 4); // 2 MB

    hipMemsetAsync(cnt, 0, (size_t)N_NODES * 4, stream);

    // Build CSR (dst-major), payload interleaved
    int eblocks = (N_EDGES + 255) / 256;
    hist_kernel<<<eblocks, 256, 0, stream>>>(dst, cnt);
    scan1_kernel<<<NB, 256, 0, stream>>>(cnt, bsums);
    scan2_kernel<<<1, 256, 0, stream>>>(bsums);
    scan3_kernel<<<NB, 256, 0, stream>>>(cnt, bsums, row_start, cursor);
    scatter_kernel<<<eblocks, 256, 0, stream>>>(src, dst, vals, cursor, epair);

    // acc init with layer-0 embeddings at gathered rows (direct from tables)
    int ablocks = (2 * BATCH * DIM) / 256;  // 2048
    acc_init_kernel<<<ablocks, 256, 0, stream>>>(users, items, emb_user, emb_item, accs);

    int sblocks = N_NODES / 4;  // 37500, 4 waves/block, 1 node/wave
    // Layer 1: gather from the two tables via split pointer
    spmm_kernel<<<sblocks, 256, 0, stream>>>(row_start, cursor, epair,
                                             emb_user, emb_item, N_USERS, bufA);
    acc_add_kernel<<<ablocks, 256, 0, stream>>>(users, items, bufA, accs);
    // Layer 2
    spmm_kernel<<<sblocks, 256, 0, stream>>>(row_start, cursor, epair,
                                             bufA, bufA, N_NODES, bufB);
    acc_add_kernel<<<ablocks, 256, 0, stream>>>(users, items, bufB, accs);
    // Layer 3
    spmm_kernel<<<sblocks, 256, 0, stream>>>(row_start, cursor, epair,
                                             bufB, bufB, N_NODES, bufA);
    acc_add_kernel<<<ablocks, 256, 0, stream>>>(users, items, bufA, accs);

    // gamma
    dot_kernel<<<(BATCH * DIM) / 256, 256, 0, stream>>>(accs, out);
}

// Round 3
// 463.474 us; speedup vs baseline: 2.2067x; 1.3444x over previous
//
#include <hip/hip_runtime.h>

// LightGCN propagation: 3x SpMM over fixed COO graph + batched dot epilogue.
// R3: CSR build rewritten as hierarchical counting sort (coarse 256-bucket
// partition, then per-bucket fine sort). All scattered writes are confined to
// single-block-owned regions -> single-XCD L2 assembles full 64B lines before
// eviction (R2's scatter wrote 8B randomly from all XCDs: 149MB WRITE_SIZE for
// a 19.2MB payload). Also kills the 2x 2.4M global-atomic passes and the
// 150K-node global scan: row_start/row_end come out of P4's LDS scan.

#define N_USERS 50000
#define N_ITEMS 100000
#define N_NODES 150000
#define N_EDGES 2400000
#define DIM 64
#define BATCH 4096

#define CHUNKS 512
#define CHUNK_EDGES 4688   // 512*4688 = 2400256 >= N_EDGES
#define KB 256             // coarse buckets
#define NPB 586            // nodes per bucket; 256*586 = 150016 >= N_NODES

// P1: per-chunk LDS histogram over coarse buckets
__global__ __launch_bounds__(256) void p1_hist(const int* __restrict__ dst,
                                               int* __restrict__ hist) {
    __shared__ int h[KB];
    int c = blockIdx.x, t = threadIdx.x;
    h[t] = 0;
    __syncthreads();
    int base = c * CHUNK_EDGES;
    for (int i = t; i < CHUNK_EDGES; i += 256) {
        int e = base + i;
        if (e < N_EDGES) atomicAdd(&h[(unsigned)dst[e] / NPB], 1);
    }
    __syncthreads();
    hist[c * KB + t] = h[t];
}

// P2: bucket-major exclusive scan of hist (in place -> per-(chunk,bucket)
// base offsets), plus bucket_base[KB+1].
__global__ __launch_bounds__(256) void p2_scan(int* __restrict__ hist,
                                               int* __restrict__ bucket_base) {
    int t = threadIdx.x;
    int tot = 0;
    for (int c = 0; c < CHUNKS; ++c) tot += hist[c * KB + t];
    __shared__ int sm[KB];
    sm[t] = tot;
    __syncthreads();
    for (int o = 1; o < 256; o <<= 1) {
        int add = (t >= o) ? sm[t - o] : 0;
        __syncthreads();
        sm[t] += add;
        __syncthreads();
    }
    int excl = sm[t] - tot;
    bucket_base[t] = excl;
    if (t == 255) bucket_base[256] = excl + tot;
    int run = excl;
    for (int c = 0; c < CHUNKS; ++c) {
        int h = hist[c * KB + t];
        hist[c * KB + t] = run;
        run += h;
    }
}

// P3: coarse partition. Each block scatters its chunk's edges into its own
// per-bucket runs (single-block-owned -> full-line L2 assembly).
// Payload packed: x = src | dst_local<<18 (src<2^18, dst_local<1024), y = val.
__global__ __launch_bounds__(256) void p3_part(const int* __restrict__ src,
                                               const int* __restrict__ dstA,
                                               const float* __restrict__ vals,
                                               const int* __restrict__ hist,
                                               int2* __restrict__ coarse) {
    __shared__ int cur[KB];
    int c = blockIdx.x, t = threadIdx.x;
    cur[t] = hist[c * KB + t];
    __syncthreads();
    int base = c * CHUNK_EDGES;
    for (int i = t; i < CHUNK_EDGES; i += 256) {
        int e = base + i;
        if (e < N_EDGES) {
            int d = dstA[e];
            int b = (int)((unsigned)d / NPB);
            int dl = d - b * NPB;
            int p = atomicAdd(&cur[b], 1);
            coarse[p] = make_int2(src[e] | (dl << 18), __float_as_int(vals[e]));
        }
    }
}

// P4: fine sort within each bucket + emit row_start/row_end.
__global__ __launch_bounds__(256) void p4_fine(const int2* __restrict__ coarse,
                                               const int* __restrict__ bucket_base,
                                               int2* __restrict__ epair,
                                               int* __restrict__ row_start,
                                               int* __restrict__ row_end) {
    int k = blockIdx.x, t = threadIdx.x;
    __shared__ int cnt[768];
    __shared__ int rs[768];
    __shared__ int sc[256];
    for (int j = t; j < 768; j += 256) cnt[j] = 0;
    __syncthreads();
    int base = bucket_base[k];
    int ne = bucket_base[k + 1] - base;
    for (int i = t; i < ne; i += 256)
        atomicAdd(&cnt[coarse[base + i].x >> 18], 1);
    __syncthreads();
    // exclusive scan over 768 (thread t owns 3t..3t+2)
    int a0 = cnt[3 * t], a1 = cnt[3 * t + 1], a2 = cnt[3 * t + 2];
    int tsum = a0 + a1 + a2;
    sc[t] = tsum;
    __syncthreads();
    for (int o = 1; o < 256; o <<= 1) {
        int add = (t >= o) ? sc[t - o] : 0;
        __syncthreads();
        sc[t] += add;
        __syncthreads();
    }
    int excl = sc[t] - tsum;
    rs[3 * t] = excl;
    rs[3 * t + 1] = excl + a0;
    rs[3 * t + 2] = excl + a0 + a1;
    __syncthreads();
    int nodes0 = k * NPB;
    int nb = min(NPB, N_NODES - nodes0);
    for (int n = t; n < nb; n += 256) {
        int r = base + rs[n];
        row_start[nodes0 + n] = r;
        row_end[nodes0 + n] = r + cnt[n];
    }
    __syncthreads();
    for (int j = t; j < 768; j += 256) cnt[j] = rs[j];  // cnt becomes cursor
    __syncthreads();
    for (int i = t; i < ne; i += 256) {
        int2 ev = coarse[base + i];
        int dl = ev.x >> 18;
        int p = atomicAdd(&cnt[dl], 1);
        epair[base + p] = make_int2(ev.x & 0x3FFFF, ev.y);
    }
}

// SpMM: one wave per node. Wave = 4 groups x 16 lanes; group g handles edges
// s+g, s+g+4, ... (2x unrolled -> 8 gathers in flight). Lane l loads float4 l
// of the source row. Cross-group reduce via shfl_xor.
__global__ __launch_bounds__(256) void spmm_kernel(
        const int* __restrict__ row_start, const int* __restrict__ row_end,
        const int2* __restrict__ epair,
        const float* __restrict__ xu, const float* __restrict__ xi, int split,
        float* __restrict__ xout) {
    int n = (blockIdx.x * 256 + threadIdx.x) >> 6;   // 150000 = 4*37500 exact
    int lane = threadIdx.x & 63;
    int g = lane >> 4;
    int l = lane & 15;
    int s = row_start[n];
    int e = row_end[n];
    float4 acc = make_float4(0.f, 0.f, 0.f, 0.f);
    for (int j = s + g; j < e; j += 8) {
        int j2 = j + 4;
        bool p2 = j2 < e;
        int2 ev1 = epair[j];
        int2 ev2 = epair[p2 ? j2 : j];
        int c1 = ev1.x;
        int c2 = ev2.x;
        float v1 = __int_as_float(ev1.y);
        float v2 = p2 ? __int_as_float(ev2.y) : 0.f;
        const float4* b1 = (const float4*)((c1 < split) ? (xu + (size_t)c1 * DIM)
                                                        : (xi + (size_t)(c1 - split) * DIM));
        const float4* b2 = (const float4*)((c2 < split) ? (xu + (size_t)c2 * DIM)
                                                        : (xi + (size_t)(c2 - split) * DIM));
        float4 x1 = b1[l];
        float4 x2 = b2[l];
        acc.x += v1 * x1.x; acc.y += v1 * x1.y; acc.z += v1 * x1.z; acc.w += v1 * x1.w;
        acc.x += v2 * x2.x; acc.y += v2 * x2.y; acc.z += v2 * x2.z; acc.w += v2 * x2.w;
    }
#pragma unroll
    for (int off = 16; off < 64; off <<= 1) {
        acc.x += __shfl_xor(acc.x, off, 64);
        acc.y += __shfl_xor(acc.y, off, 64);
        acc.z += __shfl_xor(acc.z, off, 64);
        acc.w += __shfl_xor(acc.w, off, 64);
    }
    if (g == 0) ((float4*)(xout + (size_t)n * DIM))[l] = acc;
}

__global__ void acc_init_kernel(const int* __restrict__ users, const int* __restrict__ items,
                                const float* __restrict__ emb_user, const float* __restrict__ emb_item,
                                float* __restrict__ acc) {
    int idx = blockIdx.x * 256 + threadIdx.x;
    int r = idx >> 6;
    int lane = idx & 63;
    const float* srcrow = (r < BATCH) ? (emb_user + (size_t)users[r] * DIM)
                                      : (emb_item + (size_t)items[r - BATCH] * DIM);
    acc[idx] = srcrow[lane];
}

__global__ void acc_add_kernel(const int* __restrict__ users, const int* __restrict__ items,
                               const float* __restrict__ x, float* __restrict__ acc) {
    int idx = blockIdx.x * 256 + threadIdx.x;
    int r = idx >> 6;
    int lane = idx & 63;
    int node = (r < BATCH) ? users[r] : (N_USERS + items[r - BATCH]);
    acc[idx] += x[(size_t)node * DIM + lane];
}

__global__ void dot_kernel(const float* __restrict__ acc, float* __restrict__ out) {
    int t = blockIdx.x * 256 + threadIdx.x;
    int b = t >> 6;
    int lane = t & 63;
    float p = acc[b * DIM + lane] * acc[(BATCH + b) * DIM + lane];
#pragma unroll
    for (int o = 32; o > 0; o >>= 1) p += __shfl_down(p, o, 64);
    if (lane == 0) out[b] = p * (1.0f / 16.0f);
}

extern "C" void kernel_launch(void* const* d_in, const int* in_sizes, int n_in,
                              void* d_out, int out_size, void* d_ws, size_t ws_size,
                              hipStream_t stream) {
    const float* emb_user = (const float*)d_in[0];
    const float* emb_item = (const float*)d_in[1];
    const float* vals     = (const float*)d_in[2];
    const int*   src      = (const int*)d_in[3];
    const int*   dst      = (const int*)d_in[4];
    const int*   users    = (const int*)d_in[5];
    const int*   items    = (const int*)d_in[6];
    float* out = (float*)d_out;

    char* ws = (char*)d_ws;
    size_t off = 0;
    auto walloc = [&](size_t bytes) -> void* {
        void* p = ws + off;
        off += (bytes + 255) & ~(size_t)255;
        return p;
    };
    float* bufA      = (float*)walloc((size_t)N_NODES * DIM * 4);   // 38.4 MB
    float* bufB      = (float*)walloc((size_t)N_NODES * DIM * 4);   // 38.4 MB
    int2*  epair     = (int2*) walloc((size_t)N_EDGES * 8);         // 19.2 MB
    int*   hist      = (int*)  walloc((size_t)CHUNKS * KB * 4);     // 0.5 MB
    int*   bucket_base = (int*)walloc((size_t)(KB + 1) * 4);
    int*   row_start = (int*)  walloc((size_t)N_NODES * 4);
    int*   row_end   = (int*)  walloc((size_t)N_NODES * 4);
    float* accs      = (float*)walloc((size_t)2 * BATCH * DIM * 4); // 2 MB
    // coarse partition buffer aliases bufB (dead until SpMM layer 2)
    int2* coarse = (int2*)bufB;

    // CSR build: hierarchical counting sort
    p1_hist<<<CHUNKS, 256, 0, stream>>>(dst, hist);
    p2_scan<<<1, 256, 0, stream>>>(hist, bucket_base);
    p3_part<<<CHUNKS, 256, 0, stream>>>(src, dst, vals, hist, coarse);
    p4_fine<<<KB, 256, 0, stream>>>(coarse, bucket_base, epair, row_start, row_end);

    // acc init with layer-0 embeddings at gathered rows
    int ablocks = (2 * BATCH * DIM) / 256;  // 2048
    acc_init_kernel<<<ablocks, 256, 0, stream>>>(users, items, emb_user, emb_item, accs);

    int sblocks = N_NODES / 4;  // 37500
    // Layer 1: gather straight from the two embedding tables
    spmm_kernel<<<sblocks, 256, 0, stream>>>(row_start, row_end, epair,
                                             emb_user, emb_item, N_USERS, bufA);
    acc_add_kernel<<<ablocks, 256, 0, stream>>>(users, items, bufA, accs);
    // Layer 2
    spmm_kernel<<<sblocks, 256, 0, stream>>>(row_start, row_end, epair,
                                             bufA, bufA, N_NODES, bufB);
    acc_add_kernel<<<ablocks, 256, 0, stream>>>(users, items, bufB, accs);
    // Layer 3
    spmm_kernel<<<sblocks, 256, 0, stream>>>(row_start, row_end, epair,
                                             bufB, bufB, N_NODES, bufA);
    acc_add_kernel<<<ablocks, 256, 0, stream>>>(users, items, bufA, accs);

    // gamma
    dot_kernel<<<(BATCH * DIM) / 256, 256, 0, stream>>>(accs, out);
}

// Round 4
// 443.623 us; speedup vs baseline: 2.3054x; 1.0447x over previous
//
#include <hip/hip_runtime.h>

// LightGCN propagation: 3x SpMM over fixed COO graph + batched dot epilogue.
// R4: (a) SpMM unrolled 4x -> 16 gathered rows in flight per wave (was 8);
// (b) CSR-build scan parallelized: bucket-major hist, 256-block coalesced LDS
// scans (p2a) + tiny bucket-total scan (p2b) replace the single-block serial
// p2 (one CU chewing 0.5MB with a dependent run-sum); (c) final acc_add+dot
// fused. Scatter stays hierarchical (R3): all scattered writes land in
// single-block-owned regions so one XCD's L2 assembles full lines.

#define N_USERS 50000
#define N_ITEMS 100000
#define N_NODES 150000
#define N_EDGES 2400000
#define DIM 64
#define BATCH 4096

#define CHUNKS 512
#define CHUNK_EDGES 4688   // 512*4688 = 2400256 >= N_EDGES
#define KB 256             // coarse buckets
#define NPB 586            // nodes per bucket; 256*586 = 150016 >= N_NODES

// P1: per-chunk LDS histogram over coarse buckets; bucket-major output
__global__ __launch_bounds__(256) void p1_hist(const int* __restrict__ dst,
                                               int* __restrict__ hist) {
    __shared__ int h[KB];
    int c = blockIdx.x, t = threadIdx.x;
    h[t] = 0;
    __syncthreads();
    int base = c * CHUNK_EDGES;
    for (int i = t; i < CHUNK_EDGES; i += 256) {
        int e = base + i;
        if (e < N_EDGES) atomicAdd(&h[(unsigned)dst[e] / NPB], 1);
    }
    __syncthreads();
    hist[t * CHUNKS + c] = h[t];   // bucket-major
}

// P2a: per-bucket exclusive scan over its 512 chunk counts (in place, local),
// emit bucket totals. 256 blocks, coalesced reads.
__global__ __launch_bounds__(256) void p2a_scan(int* __restrict__ hist,
                                                int* __restrict__ tot) {
    int b = blockIdx.x, t = threadIdx.x;
    int i0 = b * CHUNKS + 2 * t;
    int v0 = hist[i0], v1 = hist[i0 + 1];
    int s = v0 + v1;
    __shared__ int sm[256];
    sm[t] = s;
    __syncthreads();
    for (int o = 1; o < 256; o <<= 1) {
        int add = (t >= o) ? sm[t - o] : 0;
        __syncthreads();
        sm[t] += add;
        __syncthreads();
    }
    int excl = sm[t] - s;
    hist[i0] = excl;
    hist[i0 + 1] = excl + v0;
    if (t == 255) tot[b] = excl + s;
}

// P2b: exclusive scan of the 256 bucket totals -> bucket_base[257]
__global__ __launch_bounds__(256) void p2b_scan(const int* __restrict__ tot,
                                                int* __restrict__ bucket_base) {
    int t = threadIdx.x;
    int v = tot[t];
    __shared__ int sm[256];
    sm[t] = v;
    __syncthreads();
    for (int o = 1; o < 256; o <<= 1) {
        int add = (t >= o) ? sm[t - o] : 0;
        __syncthreads();
        sm[t] += add;
        __syncthreads();
    }
    bucket_base[t] = sm[t] - v;
    if (t == 255) bucket_base[256] = sm[t];
}

// P3: coarse partition into block-owned per-bucket runs.
// Payload packed: x = src | dst_local<<18, y = val bits.
__global__ __launch_bounds__(256) void p3_part(const int* __restrict__ src,
                                               const int* __restrict__ dstA,
                                               const float* __restrict__ vals,
                                               const int* __restrict__ hist,
                                               const int* __restrict__ bucket_base,
                                               int2* __restrict__ coarse) {
    __shared__ int cur[KB];
    int c = blockIdx.x, t = threadIdx.x;
    cur[t] = bucket_base[t] + hist[t * CHUNKS + c];
    __syncthreads();
    int base = c * CHUNK_EDGES;
    for (int i = t; i < CHUNK_EDGES; i += 256) {
        int e = base + i;
        if (e < N_EDGES) {
            int d = dstA[e];
            int b = (int)((unsigned)d / NPB);
            int dl = d - b * NPB;
            int p = atomicAdd(&cur[b], 1);
            coarse[p] = make_int2(src[e] | (dl << 18), __float_as_int(vals[e]));
        }
    }
}

// P4: fine sort within each bucket + emit row_start/row_end.
// Second pass over coarse re-reads the block's own ~75KB run (L2-hot).
__global__ __launch_bounds__(256) void p4_fine(const int2* __restrict__ coarse,
                                               const int* __restrict__ bucket_base,
                                               int2* __restrict__ epair,
                                               int* __restrict__ row_start,
                                               int* __restrict__ row_end) {
    int k = blockIdx.x, t = threadIdx.x;
    __shared__ int cnt[768];
    __shared__ int rs[768];
    __shared__ int sc[256];
    for (int j = t; j < 768; j += 256) cnt[j] = 0;
    __syncthreads();
    int base = bucket_base[k];
    int ne = bucket_base[k + 1] - base;
    for (int i = t; i < ne; i += 256)
        atomicAdd(&cnt[coarse[base + i].x >> 18], 1);
    __syncthreads();
    int a0 = cnt[3 * t], a1 = cnt[3 * t + 1], a2 = cnt[3 * t + 2];
    int tsum = a0 + a1 + a2;
    sc[t] = tsum;
    __syncthreads();
    for (int o = 1; o < 256; o <<= 1) {
        int add = (t >= o) ? sc[t - o] : 0;
        __syncthreads();
        sc[t] += add;
        __syncthreads();
    }
    int excl = sc[t] - tsum;
    rs[3 * t] = excl;
    rs[3 * t + 1] = excl + a0;
    rs[3 * t + 2] = excl + a0 + a1;
    __syncthreads();
    int nodes0 = k * NPB;
    int nb = min(NPB, N_NODES - nodes0);
    for (int n = t; n < nb; n += 256) {
        int r = base + rs[n];
        row_start[nodes0 + n] = r;
        row_end[nodes0 + n] = r + cnt[n];
    }
    __syncthreads();
    for (int j = t; j < 768; j += 256) cnt[j] = rs[j];  // cnt becomes cursor
    __syncthreads();
    for (int i = t; i < ne; i += 256) {
        int2 ev = coarse[base + i];
        int dl = ev.x >> 18;
        int p = atomicAdd(&cnt[dl], 1);
        epair[base + p] = make_int2(ev.x & 0x3FFFF, ev.y);
    }
}

// SpMM: one wave per node; 4 groups x 16 lanes; 4x unrolled -> 16 rows in
// flight per wave. Lane l loads float4 l of the source row; cross-group
// reduce via shfl_xor. Predicated tail: clamped index re-gathers a hot row
// with val=0 (cache-served, no HBM cost).
__global__ __launch_bounds__(256) void spmm_kernel(
        const int* __restrict__ row_start, const int* __restrict__ row_end,
        const int2* __restrict__ epair,
        const float* __restrict__ xu, const float* __restrict__ xi, int split,
        float* __restrict__ xout) {
    int n = (blockIdx.x * 256 + threadIdx.x) >> 6;   // 150000 = 4*37500 exact
    int lane = threadIdx.x & 63;
    int g = lane >> 4;
    int l = lane & 15;
    int s = row_start[n];
    int e = row_end[n];
    float4 acc = make_float4(0.f, 0.f, 0.f, 0.f);
    for (int j0 = s + g; j0 < e; j0 += 16) {
        int cidx[4];
        float vv[4];
#pragma unroll
        for (int u = 0; u < 4; ++u) {
            int j = j0 + 4 * u;
            bool p = j < e;
            int2 ev = epair[p ? j : j0];
            cidx[u] = ev.x;
            vv[u] = p ? __int_as_float(ev.y) : 0.f;
        }
        float4 xr[4];
#pragma unroll
        for (int u = 0; u < 4; ++u) {
            const float* bp = (cidx[u] < split) ? (xu + (size_t)cidx[u] * DIM)
                                                : (xi + (size_t)(cidx[u] - split) * DIM);
            xr[u] = ((const float4*)bp)[l];
        }
#pragma unroll
        for (int u = 0; u < 4; ++u) {
            acc.x += vv[u] * xr[u].x;
            acc.y += vv[u] * xr[u].y;
            acc.z += vv[u] * xr[u].z;
            acc.w += vv[u] * xr[u].w;
        }
    }
#pragma unroll
    for (int off = 16; off < 64; off <<= 1) {
        acc.x += __shfl_xor(acc.x, off, 64);
        acc.y += __shfl_xor(acc.y, off, 64);
        acc.z += __shfl_xor(acc.z, off, 64);
        acc.w += __shfl_xor(acc.w, off, 64);
    }
    if (g == 0) ((float4*)(xout + (size_t)n * DIM))[l] = acc;
}

__global__ void acc_init_kernel(const int* __restrict__ users, const int* __restrict__ items,
                                const float* __restrict__ emb_user, const float* __restrict__ emb_item,
                                float* __restrict__ acc) {
    int idx = blockIdx.x * 256 + threadIdx.x;
    int r = idx >> 6;
    int lane = idx & 63;
    const float* srcrow = (r < BATCH) ? (emb_user + (size_t)users[r] * DIM)
                                      : (emb_item + (size_t)items[r - BATCH] * DIM);
    acc[idx] = srcrow[lane];
}

__global__ void acc_add_kernel(const int* __restrict__ users, const int* __restrict__ items,
                               const float* __restrict__ x, float* __restrict__ acc) {
    int idx = blockIdx.x * 256 + threadIdx.x;
    int r = idx >> 6;
    int lane = idx & 63;
    int node = (r < BATCH) ? users[r] : (N_USERS + items[r - BATCH]);
    acc[idx] += x[(size_t)node * DIM + lane];
}

// Fused last-layer accumulate + dot: one wave per batch element.
// gamma[b] = dot(acc_u[b]+x3[u_b], acc_i[b]+x3[i_b]) / 16
__global__ void final_kernel(const int* __restrict__ users, const int* __restrict__ items,
                             const float* __restrict__ x, const float* __restrict__ acc,
                             float* __restrict__ out) {
    int t = blockIdx.x * 256 + threadIdx.x;
    int b = t >> 6;
    int lane = t & 63;
    int un = users[b];
    int in = N_USERS + items[b];
    float u = acc[(size_t)b * DIM + lane] + x[(size_t)un * DIM + lane];
    float v = acc[(size_t)(BATCH + b) * DIM + lane] + x[(size_t)in * DIM + lane];
    float p = u * v;
#pragma unroll
    for (int o = 32; o > 0; o >>= 1) p += __shfl_down(p, o, 64);
    if (lane == 0) out[b] = p * (1.0f / 16.0f);
}

extern "C" void kernel_launch(void* const* d_in, const int* in_sizes, int n_in,
                              void* d_out, int out_size, void* d_ws, size_t ws_size,
                              hipStream_t stream) {
    const float* emb_user = (const float*)d_in[0];
    const float* emb_item = (const float*)d_in[1];
    const float* vals     = (const float*)d_in[2];
    const int*   src      = (const int*)d_in[3];
    const int*   dst      = (const int*)d_in[4];
    const int*   users    = (const int*)d_in[5];
    const int*   items    = (const int*)d_in[6];
    float* out = (float*)d_out;

    char* ws = (char*)d_ws;
    size_t off = 0;
    auto walloc = [&](size_t bytes) -> void* {
        void* p = ws + off;
        off += (bytes + 255) & ~(size_t)255;
        return p;
    };
    float* bufA      = (float*)walloc((size_t)N_NODES * DIM * 4);   // 38.4 MB
    float* bufB      = (float*)walloc((size_t)N_NODES * DIM * 4);   // 38.4 MB
    int2*  epair     = (int2*) walloc((size_t)N_EDGES * 8);         // 19.2 MB
    int*   hist      = (int*)  walloc((size_t)CHUNKS * KB * 4);     // 0.5 MB
    int*   tot       = (int*)  walloc((size_t)KB * 4);
    int*   bucket_base = (int*)walloc((size_t)(KB + 1) * 4);
    int*   row_start = (int*)  walloc((size_t)N_NODES * 4);
    int*   row_end   = (int*)  walloc((size_t)N_NODES * 4);
    float* accs      = (float*)walloc((size_t)2 * BATCH * DIM * 4); // 2 MB
    // coarse partition buffer aliases bufB (dead until SpMM layer 2)
    int2* coarse = (int2*)bufB;

    // CSR build: hierarchical counting sort, fully parallel scan
    p1_hist<<<CHUNKS, 256, 0, stream>>>(dst, hist);
    p2a_scan<<<KB, 256, 0, stream>>>(hist, tot);
    p2b_scan<<<1, 256, 0, stream>>>(tot, bucket_base);
    p3_part<<<CHUNKS, 256, 0, stream>>>(src, dst, vals, hist, bucket_base, coarse);
    p4_fine<<<KB, 256, 0, stream>>>(coarse, bucket_base, epair, row_start, row_end);

    // acc init with layer-0 embeddings at gathered rows
    int ablocks = (2 * BATCH * DIM) / 256;  // 2048
    acc_init_kernel<<<ablocks, 256, 0, stream>>>(users, items, emb_user, emb_item, accs);

    int sblocks = N_NODES / 4;  // 37500
    // Layer 1: gather straight from the two embedding tables
    spmm_kernel<<<sblocks, 256, 0, stream>>>(row_start, row_end, epair,
                                             emb_user, emb_item, N_USERS, bufA);
    acc_add_kernel<<<ablocks, 256, 0, stream>>>(users, items, bufA, accs);
    // Layer 2
    spmm_kernel<<<sblocks, 256, 0, stream>>>(row_start, row_end, epair,
                                             bufA, bufA, N_NODES, bufB);
    acc_add_kernel<<<ablocks, 256, 0, stream>>>(users, items, bufB, accs);
    // Layer 3
    spmm_kernel<<<sblocks, 256, 0, stream>>>(row_start, row_end, epair,
                                             bufB, bufB, N_NODES, bufA);
    // fused: acc += x3 gather, dot, scale
    final_kernel<<<(BATCH * DIM) / 256, 256, 0, stream>>>(users, items, bufA, accs, out);
}

// Round 5
// 351.078 us; speedup vs baseline: 2.9132x; 1.2636x over previous
//
#include <hip/hip_runtime.h>

// LightGCN propagation: 3x SpMM over fixed COO graph + batched dot epilogue.
// R5: propagation state stored as bf16 (128B rows). R4 showed spmm pinned at
// 288MB FETCH = 8 XCDs x 38.4MB = compulsory fabric traffic for fp32 rows
// (random gather, per-XCD L2s) — doubling MLP changed nothing. Halving the
// row size halves compulsory traffic. fp32 accumulate in registers; bf16 only
// for storage (gamma err ~3e-6 << 3.6e-4 threshold). Wave = 8 groups x 8
// lanes, lane loads uint4 = 8 bf16; 16 rows in flight. Epilogue fully fused.

#define N_USERS 50000
#define N_ITEMS 100000
#define N_NODES 150000
#define N_EDGES 2400000
#define DIM 64
#define BATCH 4096

#define CHUNKS 512
#define CHUNK_EDGES 4688   // 512*4688 = 2400256 >= N_EDGES
#define KB 256             // coarse buckets
#define NPB 586            // nodes per bucket; 256*586 = 150016 >= N_NODES

typedef unsigned int uint;

__device__ __forceinline__ uint pack_bf16(float a, float b) {
    uint ua = __float_as_uint(a), ub = __float_as_uint(b);
    ua = (ua + 0x7FFFu + ((ua >> 16) & 1u)) >> 16;   // RTNE
    ub = (ub + 0x7FFFu + ((ub >> 16) & 1u)) >> 16;
    return ua | (ub << 16);
}

// Convert fp32 embedding tables -> bf16 concat t0 (32 uints per row).
__global__ __launch_bounds__(256) void conv_kernel(const float* __restrict__ emb_user,
                                                   const float* __restrict__ emb_item,
                                                   uint2* __restrict__ t0) {
    int i = blockIdx.x * 256 + threadIdx.x;            // float4 index, 2.4M total
    const int userN4 = N_USERS * DIM / 4;              // 800000
    float4 v;
    if (i < userN4) v = ((const float4*)emb_user)[i];
    else            v = ((const float4*)emb_item)[i - userN4];
    t0[i] = make_uint2(pack_bf16(v.x, v.y), pack_bf16(v.z, v.w));
}

// P1: per-chunk LDS histogram over coarse buckets; bucket-major output
__global__ __launch_bounds__(256) void p1_hist(const int* __restrict__ dst,
                                               int* __restrict__ hist) {
    __shared__ int h[KB];
    int c = blockIdx.x, t = threadIdx.x;
    h[t] = 0;
    __syncthreads();
    int base = c * CHUNK_EDGES;
    for (int i = t; i < CHUNK_EDGES; i += 256) {
        int e = base + i;
        if (e < N_EDGES) atomicAdd(&h[(unsigned)dst[e] / NPB], 1);
    }
    __syncthreads();
    hist[t * CHUNKS + c] = h[t];   // bucket-major
}

// P2a: per-bucket exclusive scan over its 512 chunk counts; emit totals.
__global__ __launch_bounds__(256) void p2a_scan(int* __restrict__ hist,
                                                int* __restrict__ tot) {
    int b = blockIdx.x, t = threadIdx.x;
    int i0 = b * CHUNKS + 2 * t;
    int v0 = hist[i0], v1 = hist[i0 + 1];
    int s = v0 + v1;
    __shared__ int sm[256];
    sm[t] = s;
    __syncthreads();
    for (int o = 1; o < 256; o <<= 1) {
        int add = (t >= o) ? sm[t - o] : 0;
        __syncthreads();
        sm[t] += add;
        __syncthreads();
    }
    int excl = sm[t] - s;
    hist[i0] = excl;
    hist[i0 + 1] = excl + v0;
    if (t == 255) tot[b] = excl + s;
}

// P2b: exclusive scan of the 256 bucket totals -> bucket_base[257]
__global__ __launch_bounds__(256) void p2b_scan(const int* __restrict__ tot,
                                                int* __restrict__ bucket_base) {
    int t = threadIdx.x;
    int v = tot[t];
    __shared__ int sm[256];
    sm[t] = v;
    __syncthreads();
    for (int o = 1; o < 256; o <<= 1) {
        int add = (t >= o) ? sm[t - o] : 0;
        __syncthreads();
        sm[t] += add;
        __syncthreads();
    }
    bucket_base[t] = sm[t] - v;
    if (t == 255) bucket_base[256] = sm[t];
}

// P3: coarse partition into block-owned per-bucket runs.
// Payload packed: x = src | dst_local<<18, y = val bits.
__global__ __launch_bounds__(256) void p3_part(const int* __restrict__ src,
                                               const int* __restrict__ dstA,
                                               const float* __restrict__ vals,
                                               const int* __restrict__ hist,
                                               const int* __restrict__ bucket_base,
                                               int2* __restrict__ coarse) {
    __shared__ int cur[KB];
    int c = blockIdx.x, t = threadIdx.x;
    cur[t] = bucket_base[t] + hist[t * CHUNKS + c];
    __syncthreads();
    int base = c * CHUNK_EDGES;
    for (int i = t; i < CHUNK_EDGES; i += 256) {
        int e = base + i;
        if (e < N_EDGES) {
            int d = dstA[e];
            int b = (int)((unsigned)d / NPB);
            int dl = d - b * NPB;
            int p = atomicAdd(&cur[b], 1);
            coarse[p] = make_int2(src[e] | (dl << 18), __float_as_int(vals[e]));
        }
    }
}

// P4: fine sort within each bucket + emit row_start/row_end.
__global__ __launch_bounds__(256) void p4_fine(const int2* __restrict__ coarse,
                                               const int* __restrict__ bucket_base,
                                               int2* __restrict__ epair,
                                               int* __restrict__ row_start,
                                               int* __restrict__ row_end) {
    int k = blockIdx.x, t = threadIdx.x;
    __shared__ int cnt[768];
    __shared__ int rs[768];
    __shared__ int sc[256];
    for (int j = t; j < 768; j += 256) cnt[j] = 0;
    __syncthreads();
    int base = bucket_base[k];
    int ne = bucket_base[k + 1] - base;
    for (int i = t; i < ne; i += 256)
        atomicAdd(&cnt[coarse[base + i].x >> 18], 1);
    __syncthreads();
    int a0 = cnt[3 * t], a1 = cnt[3 * t + 1], a2 = cnt[3 * t + 2];
    int tsum = a0 + a1 + a2;
    sc[t] = tsum;
    __syncthreads();
    for (int o = 1; o < 256; o <<= 1) {
        int add = (t >= o) ? sc[t - o] : 0;
        __syncthreads();
        sc[t] += add;
        __syncthreads();
    }
    int excl = sc[t] - tsum;
    rs[3 * t] = excl;
    rs[3 * t + 1] = excl + a0;
    rs[3 * t + 2] = excl + a0 + a1;
    __syncthreads();
    int nodes0 = k * NPB;
    int nb = min(NPB, N_NODES - nodes0);
    for (int n = t; n < nb; n += 256) {
        int r = base + rs[n];
        row_start[nodes0 + n] = r;
        row_end[nodes0 + n] = r + cnt[n];
    }
    __syncthreads();
    for (int j = t; j < 768; j += 256) cnt[j] = rs[j];  // cnt becomes cursor
    __syncthreads();
    for (int i = t; i < ne; i += 256) {
        int2 ev = coarse[base + i];
        int dl = ev.x >> 18;
        int p = atomicAdd(&cnt[dl], 1);
        epair[base + p] = make_int2(ev.x & 0x3FFFF, ev.y);
    }
}

// SpMM over bf16 rows (32 uints = 128B/row). One wave per node; 8 groups x
// 8 lanes; group g handles edges s+g, s+g+8, ... 2x unrolled -> 16 rows in
// flight. Lane l loads uint4 (8 bf16) covering dims [8l,8l+7]; fp32 FMA in
// registers; cross-group reduce via shfl_xor; group 0 packs + writes bf16.
__global__ __launch_bounds__(256) void spmm_kernel(
        const int* __restrict__ row_start, const int* __restrict__ row_end,
        const int2* __restrict__ epair,
        const uint* __restrict__ xin, uint* __restrict__ xout) {
    int n = (blockIdx.x * 256 + threadIdx.x) >> 6;   // 150000 = 4*37500 exact
    int lane = threadIdx.x & 63;
    int g = lane >> 3;        // edge group 0..7
    int l = lane & 7;         // uint4 slot within row
    int s = row_start[n];
    int e = row_end[n];
    float a[8];
#pragma unroll
    for (int k = 0; k < 8; ++k) a[k] = 0.f;
    for (int j0 = s + g; j0 < e; j0 += 16) {
        int j1 = j0 + 8;
        bool p1 = j1 < e;
        int2 ev0 = epair[j0];
        int2 ev1 = epair[p1 ? j1 : j0];
        float v0 = __int_as_float(ev0.y);
        float v1 = p1 ? __int_as_float(ev1.y) : 0.f;
        uint4 r0 = ((const uint4*)(xin + (size_t)ev0.x * 32))[l];
        uint4 r1 = ((const uint4*)(xin + (size_t)ev1.x * 32))[l];
        uint w0[4] = {r0.x, r0.y, r0.z, r0.w};
        uint w1[4] = {r1.x, r1.y, r1.z, r1.w};
#pragma unroll
        for (int k = 0; k < 4; ++k) {
            a[2 * k]     += v0 * __uint_as_float(w0[k] << 16);
            a[2 * k + 1] += v0 * __uint_as_float(w0[k] & 0xFFFF0000u);
            a[2 * k]     += v1 * __uint_as_float(w1[k] << 16);
            a[2 * k + 1] += v1 * __uint_as_float(w1[k] & 0xFFFF0000u);
        }
    }
#pragma unroll
    for (int off = 8; off < 64; off <<= 1) {
#pragma unroll
        for (int k = 0; k < 8; ++k) a[k] += __shfl_xor(a[k], off, 64);
    }
    if (g == 0) {
        uint4 o;
        o.x = pack_bf16(a[0], a[1]);
        o.y = pack_bf16(a[2], a[3]);
        o.z = pack_bf16(a[4], a[5]);
        o.w = pack_bf16(a[6], a[7]);
        ((uint4*)(xout + (size_t)n * 32))[l] = o;
    }
}

// Fused epilogue: one wave per batch element, lane = dim.
// gamma[b] = dot(x0u+x1u+x2u+x3u, x0i+x1i+x2i+x3i) / 16
__global__ __launch_bounds__(256) void final_kernel(
        const int* __restrict__ users, const int* __restrict__ items,
        const float* __restrict__ emb_user, const float* __restrict__ emb_item,
        const unsigned short* __restrict__ x1, const unsigned short* __restrict__ x2,
        const unsigned short* __restrict__ x3, float* __restrict__ out) {
    int t = blockIdx.x * 256 + threadIdx.x;
    int b = t >> 6;
    int lane = t & 63;
    int un = users[b];
    int in = N_USERS + items[b];
    size_t uo = (size_t)un * DIM + lane;
    size_t io = (size_t)in * DIM + lane;
    float u = emb_user[uo]
            + __uint_as_float((uint)x1[uo] << 16)
            + __uint_as_float((uint)x2[uo] << 16)
            + __uint_as_float((uint)x3[uo] << 16);
    float v = emb_item[(size_t)items[b] * DIM + lane]
            + __uint_as_float((uint)x1[io] << 16)
            + __uint_as_float((uint)x2[io] << 16)
            + __uint_as_float((uint)x3[io] << 16);
    float p = u * v;
#pragma unroll
    for (int o = 32; o > 0; o >>= 1) p += __shfl_down(p, o, 64);
    if (lane == 0) out[b] = p * (1.0f / 16.0f);
}

extern "C" void kernel_launch(void* const* d_in, const int* in_sizes, int n_in,
                              void* d_out, int out_size, void* d_ws, size_t ws_size,
                              hipStream_t stream) {
    const float* emb_user = (const float*)d_in[0];
    const float* emb_item = (const float*)d_in[1];
    const float* vals     = (const float*)d_in[2];
    const int*   src      = (const int*)d_in[3];
    const int*   dst      = (const int*)d_in[4];
    const int*   users    = (const int*)d_in[5];
    const int*   items    = (const int*)d_in[6];
    float* out = (float*)d_out;

    char* ws = (char*)d_ws;
    size_t off = 0;
    auto walloc = [&](size_t bytes) -> void* {
        void* p = ws + off;
        off += (bytes + 255) & ~(size_t)255;
        return p;
    };
    const size_t ROWB = (size_t)N_NODES * DIM * 2;                  // 19.2 MB
    uint* t0         = (uint*)walloc(ROWB);                         // bf16 x0
    uint* x1         = (uint*)walloc(ROWB);
    uint* x2         = (uint*)walloc(ROWB);
    uint* x3         = (uint*)walloc(ROWB);                         // aliases coarse
    int2* epair      = (int2*)walloc((size_t)N_EDGES * 8);          // 19.2 MB
    int*  hist       = (int*) walloc((size_t)CHUNKS * KB * 4);      // 0.5 MB
    int*  tot        = (int*) walloc((size_t)KB * 4);
    int*  bucket_base= (int*) walloc((size_t)(KB + 1) * 4);
    int*  row_start  = (int*) walloc((size_t)N_NODES * 4);
    int*  row_end    = (int*) walloc((size_t)N_NODES * 4);
    // coarse (N_EDGES*8 = 19.2 MB) aliases x3: dead once p4 completes,
    // x3 first written by SpMM layer 3 (after p4). Sizes are exactly equal.
    int2* coarse = (int2*)x3;

    // bf16 conversion of the concat embedding table
    conv_kernel<<<(N_NODES * DIM / 4) / 256, 256, 0, stream>>>(emb_user, emb_item, (uint2*)t0);

    // CSR build: hierarchical counting sort, fully parallel scan
    p1_hist<<<CHUNKS, 256, 0, stream>>>(dst, hist);
    p2a_scan<<<KB, 256, 0, stream>>>(hist, tot);
    p2b_scan<<<1, 256, 0, stream>>>(tot, bucket_base);
    p3_part<<<CHUNKS, 256, 0, stream>>>(src, dst, vals, hist, bucket_base, coarse);
    p4_fine<<<KB, 256, 0, stream>>>(coarse, bucket_base, epair, row_start, row_end);

    int sblocks = N_NODES / 4;  // 37500
    spmm_kernel<<<sblocks, 256, 0, stream>>>(row_start, row_end, epair, t0, x1);
    spmm_kernel<<<sblocks, 256, 0, stream>>>(row_start, row_end, epair, x1, x2);
    spmm_kernel<<<sblocks, 256, 0, stream>>>(row_start, row_end, epair, x2, x3);

    // fused epilogue
    final_kernel<<<(BATCH * DIM) / 256, 256, 0, stream>>>(
        users, items, emb_user, emb_item,
        (const unsigned short*)x1, (const unsigned short*)x2, (const unsigned short*)x3, out);
}

// Round 6
// 335.347 us; speedup vs baseline: 3.0498x; 1.0469x over previous
//
#include <hip/hip_runtime.h>
#include <hip/hip_bf16.h>

// LightGCN propagation: 3x SpMM over fixed COO graph + batched dot epilogue.
// R6: (a) p4 fine-sort at 1024 thr/block (was 256; it runs 1 block/CU so
// intra-block parallelism is the only lever); (b) conv fused into p1 (indep
// work overlaps); (c) spmm unpack via __bfloat1622float2 (packed cvt) +
// float2 accumulators (encourage v_pk_fma_f32) to cut the 65% VALUBusy.
// bf16 row storage (R5): compulsory fabric traffic = 8 XCD x 19.2MB.

#define N_USERS 50000
#define N_ITEMS 100000
#define N_NODES 150000
#define N_EDGES 2400000
#define DIM 64
#define BATCH 4096

#define CHUNKS 512
#define CHUNK_EDGES 4688   // 512*4688 = 2400256 >= N_EDGES
#define KB 256             // coarse buckets
#define NPB 586            // nodes per bucket; 256*586 = 150016 >= N_NODES
#define CONVB ((N_NODES * DIM / 4) / 256)   // 9375 conv blocks

typedef unsigned int uint;

__device__ __forceinline__ uint pack_bf16(float a, float b) {
    uint ua = __float_as_uint(a), ub = __float_as_uint(b);
    ua = (ua + 0x7FFFu + ((ua >> 16) & 1u)) >> 16;   // RTNE
    ub = (ub + 0x7FFFu + ((ub >> 16) & 1u)) >> 16;
    return ua | (ub << 16);
}

// Fused P1 + conv: blocks [0,CHUNKS) do the per-chunk coarse histogram;
// blocks [CHUNKS, CHUNKS+CONVB) convert fp32 tables -> bf16 concat t0.
__global__ __launch_bounds__(256) void p1_hist_conv(
        const int* __restrict__ dst, int* __restrict__ hist,
        const float* __restrict__ emb_user, const float* __restrict__ emb_item,
        uint2* __restrict__ t0) {
    int t = threadIdx.x;
    if (blockIdx.x < CHUNKS) {
        __shared__ int h[KB];
        int c = blockIdx.x;
        h[t] = 0;
        __syncthreads();
        int base = c * CHUNK_EDGES;
        for (int i = t; i < CHUNK_EDGES; i += 256) {
            int e = base + i;
            if (e < N_EDGES) atomicAdd(&h[(unsigned)dst[e] / NPB], 1);
        }
        __syncthreads();
        hist[t * CHUNKS + c] = h[t];   // bucket-major
    } else {
        int i = (blockIdx.x - CHUNKS) * 256 + t;       // float4 index, 2.4M total
        const int userN4 = N_USERS * DIM / 4;          // 800000
        float4 v;
        if (i < userN4) v = ((const float4*)emb_user)[i];
        else            v = ((const float4*)emb_item)[i - userN4];
        t0[i] = make_uint2(pack_bf16(v.x, v.y), pack_bf16(v.z, v.w));
    }
}

// P2a: per-bucket exclusive scan over its 512 chunk counts; emit totals.
__global__ __launch_bounds__(256) void p2a_scan(int* __restrict__ hist,
                                                int* __restrict__ tot) {
    int b = blockIdx.x, t = threadIdx.x;
    int i0 = b * CHUNKS + 2 * t;
    int v0 = hist[i0], v1 = hist[i0 + 1];
    int s = v0 + v1;
    __shared__ int sm[256];
    sm[t] = s;
    __syncthreads();
    for (int o = 1; o < 256; o <<= 1) {
        int add = (t >= o) ? sm[t - o] : 0;
        __syncthreads();
        sm[t] += add;
        __syncthreads();
    }
    int excl = sm[t] - s;
    hist[i0] = excl;
    hist[i0 + 1] = excl + v0;
    if (t == 255) tot[b] = excl + s;
}

// P2b: exclusive scan of the 256 bucket totals -> bucket_base[257]
__global__ __launch_bounds__(256) void p2b_scan(const int* __restrict__ tot,
                                                int* __restrict__ bucket_base) {
    int t = threadIdx.x;
    int v = tot[t];
    __shared__ int sm[256];
    sm[t] = v;
    __syncthreads();
    for (int o = 1; o < 256; o <<= 1) {
        int add = (t >= o) ? sm[t - o] : 0;
        __syncthreads();
        sm[t] += add;
        __syncthreads();
    }
    bucket_base[t] = sm[t] - v;
    if (t == 255) bucket_base[256] = sm[t];
}

// P3: coarse partition into block-owned per-bucket runs.
// Payload packed: x = src | dst_local<<18, y = val bits.
__global__ __launch_bounds__(256) void p3_part(const int* __restrict__ src,
                                               const int* __restrict__ dstA,
                                               const float* __restrict__ vals,
                                               const int* __restrict__ hist,
                                               const int* __restrict__ bucket_base,
                                               int2* __restrict__ coarse) {
    __shared__ int cur[KB];
    int c = blockIdx.x, t = threadIdx.x;
    cur[t] = bucket_base[t] + hist[t * CHUNKS + c];
    __syncthreads();
    int base = c * CHUNK_EDGES;
    for (int i = t; i < CHUNK_EDGES; i += 256) {
        int e = base + i;
        if (e < N_EDGES) {
            int d = dstA[e];
            int b = (int)((unsigned)d / NPB);
            int dl = d - b * NPB;
            int p = atomicAdd(&cur[b], 1);
            coarse[p] = make_int2(src[e] | (dl << 18), __float_as_int(vals[e]));
        }
    }
}

// P4: fine sort within each bucket + emit row_start/row_end. 1024 threads.
__global__ __launch_bounds__(1024) void p4_fine(const int2* __restrict__ coarse,
                                                const int* __restrict__ bucket_base,
                                                int2* __restrict__ epair,
                                                int* __restrict__ row_start,
                                                int* __restrict__ row_end) {
    int k = blockIdx.x, t = threadIdx.x;
    __shared__ int cnt[768];
    __shared__ int rs[768];
    __shared__ int sm[1024];
    if (t < 768) cnt[t] = 0;
    __syncthreads();
    int base = bucket_base[k];
    int ne = bucket_base[k + 1] - base;
    for (int i = t; i < ne; i += 1024)
        atomicAdd(&cnt[coarse[base + i].x >> 18], 1);
    __syncthreads();
    // 1024-wide Hillis-Steele inclusive scan (768 live counters, rest zero)
    int v = (t < 768) ? cnt[t] : 0;
    sm[t] = v;
    __syncthreads();
    for (int o = 1; o < 1024; o <<= 1) {
        int add = (t >= o) ? sm[t - o] : 0;
        __syncthreads();
        sm[t] += add;
        __syncthreads();
    }
    if (t < 768) rs[t] = sm[t] - v;   // exclusive prefix within bucket
    __syncthreads();
    int nodes0 = k * NPB;
    int nb = min(NPB, N_NODES - nodes0);
    if (t < nb) {
        int r = base + rs[t];
        row_start[nodes0 + t] = r;
        row_end[nodes0 + t] = r + cnt[t];
    }
    __syncthreads();
    if (t < 768) cnt[t] = rs[t];      // cnt becomes cursor
    __syncthreads();
    for (int i = t; i < ne; i += 1024) {
        int2 ev = coarse[base + i];
        int dl = ev.x >> 18;
        int p = atomicAdd(&cnt[dl], 1);
        epair[base + p] = make_int2(ev.x & 0x3FFFF, ev.y);
    }
}

// SpMM over bf16 rows (32 uints = 128B/row). One wave per node; 8 groups x
// 8 lanes; 2x unrolled -> 16 rows in flight. Lane l loads uint4 (8 bf16);
// packed bf16->f32 cvt + float2 accumulate (v_pk_fma_f32); fp32 accumulation.
__global__ __launch_bounds__(256) void spmm_kernel(
        const int* __restrict__ row_start, const int* __restrict__ row_end,
        const int2* __restrict__ epair,
        const uint* __restrict__ xin, uint* __restrict__ xout) {
    int n = (blockIdx.x * 256 + threadIdx.x) >> 6;   // 150000 = 4*37500 exact
    int lane = threadIdx.x & 63;
    int g = lane >> 3;        // edge group 0..7
    int l = lane & 7;         // uint4 slot within row
    int s = row_start[n];
    int e = row_end[n];
    float2 a[4];
#pragma unroll
    for (int k = 0; k < 4; ++k) a[k] = make_float2(0.f, 0.f);
    for (int j0 = s + g; j0 < e; j0 += 16) {
        int j1 = j0 + 8;
        bool p1 = j1 < e;
        int2 ev0 = epair[j0];
        int2 ev1 = epair[p1 ? j1 : j0];
        float v0 = __int_as_float(ev0.y);
        float v1 = p1 ? __int_as_float(ev1.y) : 0.f;
        uint4 r0 = ((const uint4*)(xin + (size_t)ev0.x * 32))[l];
        uint4 r1 = ((const uint4*)(xin + (size_t)ev1.x * 32))[l];
        uint w0[4] = {r0.x, r0.y, r0.z, r0.w};
        uint w1[4] = {r1.x, r1.y, r1.z, r1.w};
#pragma unroll
        for (int k = 0; k < 4; ++k) {
            float2 f0 = __bfloat1622float2(*reinterpret_cast<__hip_bfloat162*>(&w0[k]));
            float2 f1 = __bfloat1622float2(*reinterpret_cast<__hip_bfloat162*>(&w1[k]));
            a[k].x += v0 * f0.x;
            a[k].y += v0 * f0.y;
            a[k].x += v1 * f1.x;
            a[k].y += v1 * f1.y;
        }
    }
#pragma unroll
    for (int off = 8; off < 64; off <<= 1) {
#pragma unroll
        for (int k = 0; k < 4; ++k) {
            a[k].x += __shfl_xor(a[k].x, off, 64);
            a[k].y += __shfl_xor(a[k].y, off, 64);
        }
    }
    if (g == 0) {
        uint4 o;
        o.x = pack_bf16(a[0].x, a[0].y);
        o.y = pack_bf16(a[1].x, a[1].y);
        o.z = pack_bf16(a[2].x, a[2].y);
        o.w = pack_bf16(a[3].x, a[3].y);
        ((uint4*)(xout + (size_t)n * 32))[l] = o;
    }
}

// Fused epilogue: one wave per batch element, lane = dim.
// gamma[b] = dot(x0u+x1u+x2u+x3u, x0i+x1i+x2i+x3i) / 16
__global__ __launch_bounds__(256) void final_kernel(
        const int* __restrict__ users, const int* __restrict__ items,
        const float* __restrict__ emb_user, const float* __restrict__ emb_item,
        const unsigned short* __restrict__ x1, const unsigned short* __restrict__ x2,
        const unsigned short* __restrict__ x3, float* __restrict__ out) {
    int t = blockIdx.x * 256 + threadIdx.x;
    int b = t >> 6;
    int lane = t & 63;
    int un = users[b];
    int in = N_USERS + items[b];
    size_t uo = (size_t)un * DIM + lane;
    size_t io = (size_t)in * DIM + lane;
    float u = emb_user[uo]
            + __uint_as_float((uint)x1[uo] << 16)
            + __uint_as_float((uint)x2[uo] << 16)
            + __uint_as_float((uint)x3[uo] << 16);
    float v = emb_item[(size_t)items[b] * DIM + lane]
            + __uint_as_float((uint)x1[io] << 16)
            + __uint_as_float((uint)x2[io] << 16)
            + __uint_as_float((uint)x3[io] << 16);
    float p = u * v;
#pragma unroll
    for (int o = 32; o > 0; o >>= 1) p += __shfl_down(p, o, 64);
    if (lane == 0) out[b] = p * (1.0f / 16.0f);
}

extern "C" void kernel_launch(void* const* d_in, const int* in_sizes, int n_in,
                              void* d_out, int out_size, void* d_ws, size_t ws_size,
                              hipStream_t stream) {
    const float* emb_user = (const float*)d_in[0];
    const float* emb_item = (const float*)d_in[1];
    const float* vals     = (const float*)d_in[2];
    const int*   src      = (const int*)d_in[3];
    const int*   dst      = (const int*)d_in[4];
    const int*   users    = (const int*)d_in[5];
    const int*   items    = (const int*)d_in[6];
    float* out = (float*)d_out;

    char* ws = (char*)d_ws;
    size_t off = 0;
    auto walloc = [&](size_t bytes) -> void* {
        void* p = ws + off;
        off += (bytes + 255) & ~(size_t)255;
        return p;
    };
    const size_t ROWB = (size_t)N_NODES * DIM * 2;                  // 19.2 MB
    uint* t0         = (uint*)walloc(ROWB);                         // bf16 x0
    uint* x1         = (uint*)walloc(ROWB);
    uint* x2         = (uint*)walloc(ROWB);
    uint* x3         = (uint*)walloc(ROWB);                         // aliases coarse
    int2* epair      = (int2*)walloc((size_t)N_EDGES * 8);          // 19.2 MB
    int*  hist       = (int*) walloc((size_t)CHUNKS * KB * 4);      // 0.5 MB
    int*  tot        = (int*) walloc((size_t)KB * 4);
    int*  bucket_base= (int*) walloc((size_t)(KB + 1) * 4);
    int*  row_start  = (int*) walloc((size_t)N_NODES * 4);
    int*  row_end    = (int*) walloc((size_t)N_NODES * 4);
    // coarse (N_EDGES*8 = 19.2 MB) aliases x3: dead once p4 completes,
    // x3 first written by SpMM layer 3 (after p4). Sizes are exactly equal.
    int2* coarse = (int2*)x3;

    // CSR build (+ fused bf16 conversion)
    p1_hist_conv<<<CHUNKS + CONVB, 256, 0, stream>>>(dst, hist, emb_user, emb_item, (uint2*)t0);
    p2a_scan<<<KB, 256, 0, stream>>>(hist, tot);
    p2b_scan<<<1, 256, 0, stream>>>(tot, bucket_base);
    p3_part<<<CHUNKS, 256, 0, stream>>>(src, dst, vals, hist, bucket_base, coarse);
    p4_fine<<<KB, 1024, 0, stream>>>(coarse, bucket_base, epair, row_start, row_end);

    int sblocks = N_NODES / 4;  // 37500
    spmm_kernel<<<sblocks, 256, 0, stream>>>(row_start, row_end, epair, t0, x1);
    spmm_kernel<<<sblocks, 256, 0, stream>>>(row_start, row_end, epair, x1, x2);
    spmm_kernel<<<sblocks, 256, 0, stream>>>(row_start, row_end, epair, x2, x3);

    // fused epilogue
    final_kernel<<<(BATCH * DIM) / 256, 256, 0, stream>>>(
        users, items, emb_user, emb_item,
        (const unsigned short*)x1, (const unsigned short*)x2, (const unsigned short*)x3, out);
}